// Round 17
// baseline (470.591 us; speedup 1.0000x reference)
//
#include <hip/hip_runtime.h>
#include <hip/hip_bf16.h>
#include <math.h>

// GraphEncoder: 3x GCNConv (relu) -> global_mean_pool -> two linear heads.
// N=100000, E=1600000, G=2048, feats 10->128->256->256->64(x2)
//
// Round-17: fused agg+transform per layer (layers 2,3). Phase A gathers 16
// nodes into an LDS tile (bit-identical agg loop; SB round-trip was bf16
// anyway), phase B MFMAs from LDS (chunk-XOR swizzle), LDS-staged vectorized
// store (round-16 epilogue). Kills the 51MB SB write + 51MB re-read and two
// dispatches; MFMA overlaps gather across blocks. B-frags preloaded per block
// (1024 persistent blocks, launch_bounds(256,2)).
// Round-14/15/16 proven set otherwise frozen.

#define THREADS 256
#define SCAN_CHUNK 4096

typedef __attribute__((ext_vector_type(8))) short bf16x8;
typedef __attribute__((ext_vector_type(4))) float f32x4;

// ---------------- fused setup: deg=1, W2T, W3T, goff boundaries ----------------
__global__ void setup_kernel(int* deg,
                             const float* __restrict__ W2, __hip_bfloat16* __restrict__ W2T,
                             const float* __restrict__ W3, __hip_bfloat16* __restrict__ W3T,
                             const int* __restrict__ batch, int* goff,
                             int n, int g) {
    int i = blockIdx.x * blockDim.x + threadIdx.x;
    if (i < n) deg[i] = 1;                       // self-loop
    int r2 = i - n;
    if (r2 >= 0 && r2 < 128 * 256) {
        int k = r2 >> 8, c = r2 & 255;
        W2T[c * 128 + k] = __float2bfloat16(W2[r2]);
    }
    int r3 = i - n - 128 * 256;
    if (r3 >= 0 && r3 < 256 * 256) {
        int k = r3 >> 8, c = r3 & 255;
        W3T[c * 256 + k] = __float2bfloat16(W3[r3]);
    }
    int r4 = i - n - 128 * 256 - 256 * 256;
    if (r4 >= 0 && r4 < n) {
        int j = r4;
        int b = batch[j];
        if (j == 0) {
            for (int q = 0; q <= b; ++q) goff[q] = 0;
        } else {
            int bp = batch[j - 1];
            for (int q = bp + 1; q <= b; ++q) goff[q] = j;
        }
        if (j == n - 1) {
            for (int q = b + 1; q <= g; ++q) goff[q] = n;
        }
    }
}

// ---------------- XCD-pinned indegree histogram, uint4 edge reads -------------
__global__ __launch_bounds__(THREADS) void hist_deg_kernel(
        const int* __restrict__ dst, int* deg, int e, int n) {
    const int slice = blockIdx.x & 7;
    const int sliceSize = (n + 7) / 8;
    const int lo = slice * sliceSize;
    const int hi = lo + sliceSize;
    const int tid = (blockIdx.x >> 3) * blockDim.x + threadIdx.x;
    const int nthr = (gridDim.x >> 3) * blockDim.x;
    const int e4 = e >> 2;
    const uint4* dst4 = reinterpret_cast<const uint4*>(dst);
    for (int i = tid; i < e4; i += nthr) {
        uint4 dv = dst4[i];
        int dd[4] = {(int)dv.x, (int)dv.y, (int)dv.z, (int)dv.w};
#pragma unroll
        for (int q = 0; q < 4; ++q)
            if (dd[q] >= lo && dd[q] < hi) atomicAdd(&deg[dd[q]], 1);
    }
    for (int i = (e & ~3) + tid; i < e; i += nthr) {
        int d = dst[i];
        if (d >= lo && d < hi) atomicAdd(&deg[d], 1);
    }
}

// ---------------- parallel scan, phase 1: per-chunk indegree sums ----------------
__global__ __launch_bounds__(1024) void scan_part_kernel(
        const int* __restrict__ deg, int* __restrict__ bsum, int n) {
    __shared__ int ws[16];
    const int lane = threadIdx.x & 63;
    const int wid = threadIdx.x >> 6;
    int i0 = blockIdx.x * SCAN_CHUNK + threadIdx.x * 4;
    int s = 0;
#pragma unroll
    for (int q = 0; q < 4; ++q) {
        int i = i0 + q;
        if (i < n) s += deg[i] - 1;
    }
#pragma unroll
    for (int off = 32; off > 0; off >>= 1) s += __shfl_down(s, off, 64);
    if (lane == 0) ws[wid] = s;
    __syncthreads();
    if (threadIdx.x == 0) {
        int t = 0;
        for (int w = 0; w < 16; ++w) t += ws[w];
        bsum[blockIdx.x] = t;
    }
}

__device__ __forceinline__ unsigned pack2(float a, float b) {
    unsigned short ua = __builtin_bit_cast(unsigned short, __float2bfloat16(a));
    unsigned short ub = __builtin_bit_cast(unsigned short, __float2bfloat16(b));
    return (unsigned)ua | ((unsigned)ub << 16);
}

// ---------------- parallel scan, phase 2: scan + row_ptr/cursor/dis + xd pack ----
__global__ __launch_bounds__(1024) void scan_final_kernel(
        const int* __restrict__ deg, const int* __restrict__ bsum, int nb,
        int* __restrict__ row_ptr, int* __restrict__ cursor,
        float* __restrict__ dis, const float* __restrict__ x,
        __hip_bfloat16* __restrict__ xd, int n) {
    __shared__ int wsum[16];
    __shared__ int sbase;
    const int lane = threadIdx.x & 63;
    const int wid = threadIdx.x >> 6;
    if (threadIdx.x == 0) {
        int t = 0;
        for (int b = 0; b < blockIdx.x; ++b) t += bsum[b];
        sbase = t;
        if (blockIdx.x == 0) {
            int tot = 0;
            for (int b = 0; b < nb; ++b) tot += bsum[b];
            row_ptr[n] = tot;
        }
    }
    int i0 = blockIdx.x * SCAN_CHUNK + threadIdx.x * 4;
    int v[4];
#pragma unroll
    for (int q = 0; q < 4; ++q) {
        int i = i0 + q;
        v[q] = (i < n) ? (deg[i] - 1) : 0;
    }
    int tsum = v[0] + v[1] + v[2] + v[3];
    int incl = tsum;
#pragma unroll
    for (int off = 1; off < 64; off <<= 1) {
        int t = __shfl_up(incl, off, 64);
        if (lane >= off) incl += t;
    }
    if (lane == 63) wsum[wid] = incl;
    __syncthreads();
    int wbase = 0;
    for (int w = 0; w < wid; ++w) wbase += wsum[w];
    int pos = incl - tsum + wbase + sbase;
    uint4* xd4 = reinterpret_cast<uint4*>(xd);
#pragma unroll
    for (int q = 0; q < 4; ++q) {
        int i = i0 + q;
        if (i < n) {
            row_ptr[i] = pos;
            cursor[i] = pos;
            float dv = rsqrtf((float)(v[q] + 1));
            dis[i] = dv;
            unsigned ow[8];
#pragma unroll
            for (int k = 0; k < 5; ++k)
                ow[k] = pack2(x[(size_t)i * 10 + 2 * k] * dv,
                              x[(size_t)i * 10 + 2 * k + 1] * dv);
            ow[5] = 0; ow[6] = 0; ow[7] = 0;
            xd4[(size_t)i * 2]     = make_uint4(ow[0], ow[1], ow[2], ow[3]);
            xd4[(size_t)i * 2 + 1] = make_uint4(ow[4], ow[5], ow[6], ow[7]);
        }
        pos += v[q];
    }
}

// ---------------- XCD-pinned CSR fill, uint4 edge reads ----------------
__global__ __launch_bounds__(THREADS) void fill_csr_kernel(
        const int* __restrict__ src, const int* __restrict__ dst,
        int* cursor, int* __restrict__ col, int e, int n) {
    const int slice = blockIdx.x & 7;
    const int sliceSize = (n + 7) / 8;
    const int lo = slice * sliceSize;
    const int hi = lo + sliceSize;
    const int tid = (blockIdx.x >> 3) * blockDim.x + threadIdx.x;
    const int nthr = (gridDim.x >> 3) * blockDim.x;
    const int e4 = e >> 2;
    const uint4* dst4 = reinterpret_cast<const uint4*>(dst);
    const uint4* src4 = reinterpret_cast<const uint4*>(src);
    for (int i = tid; i < e4; i += nthr) {
        uint4 dv = dst4[i];
        int dd[4] = {(int)dv.x, (int)dv.y, (int)dv.z, (int)dv.w};
        bool any = false;
#pragma unroll
        for (int q = 0; q < 4; ++q) any |= (dd[q] >= lo && dd[q] < hi);
        if (!any) continue;
        uint4 sv = src4[i];
        int ss[4] = {(int)sv.x, (int)sv.y, (int)sv.z, (int)sv.w};
#pragma unroll
        for (int q = 0; q < 4; ++q) {
            if (dd[q] >= lo && dd[q] < hi) {
                int pos = atomicAdd(&cursor[dd[q]], 1);
                col[pos] = ss[q];
            }
        }
    }
    for (int i = (e & ~3) + tid; i < e; i += nthr) {
        int d = dst[i];
        if (d >= lo && d < hi) {
            int pos = atomicAdd(&cursor[d], 1);
            col[pos] = src[i];
        }
    }
}

// ---------------- bf16 helpers ----------------
__device__ __forceinline__ void acc8(float* acc, uint4 v) {
    acc[0] += __uint_as_float(v.x << 16);
    acc[1] += __uint_as_float(v.x & 0xffff0000u);
    acc[2] += __uint_as_float(v.y << 16);
    acc[3] += __uint_as_float(v.y & 0xffff0000u);
    acc[4] += __uint_as_float(v.z << 16);
    acc[5] += __uint_as_float(v.z & 0xffff0000u);
    acc[6] += __uint_as_float(v.w << 16);
    acc[7] += __uint_as_float(v.w & 0xffff0000u);
}

// ---------------- fused layer 1: 2-lane uint4 xd gather + 10->128 transform ----
__global__ __launch_bounds__(THREADS) void layer1_kernel(
        const __hip_bfloat16* __restrict__ xd, const int* __restrict__ row_ptr,
        const int* __restrict__ col, const float* __restrict__ dis,
        const float* __restrict__ W1, const float* __restrict__ b1,
        __hip_bfloat16* __restrict__ out, int n) {
    __shared__ float h[128][12];
    __shared__ float w[10][128];
    __shared__ float bias[128];

    for (int idx = threadIdx.x; idx < 1280; idx += THREADS)
        w[idx >> 7][idx & 127] = W1[idx];
    if (threadIdx.x < 128) bias[threadIdx.x] = b1[threadIdx.x];

    const int node0 = blockIdx.x * 128;
    const int nl = threadIdx.x >> 1;
    const int lane = threadIdx.x & 1;
    const int node = node0 + nl;
    const uint4* S4 = reinterpret_cast<const uint4*>(xd);

    if (node < n) {
        float acc[8];
#pragma unroll
        for (int q = 0; q < 8; ++q) acc[q] = 0.f;
        acc8(acc, S4[(size_t)node * 2 + lane]);   // self (xd = x*dis)

        int s = row_ptr[node], e = row_ptr[node + 1];
        int p = s;
        for (; p + 8 <= e; p += 8) {
            int j[8];
#pragma unroll
            for (int q = 0; q < 8; ++q) j[q] = col[p + q];
            uint4 v[8];
#pragma unroll
            for (int q = 0; q < 8; ++q) v[q] = S4[(size_t)j[q] * 2 + lane];
#pragma unroll
            for (int q = 0; q < 8; ++q) acc8(acc, v[q]);
        }
        for (; p < e; ++p) acc8(acc, S4[(size_t)col[p] * 2 + lane]);

        float dn = dis[node];
        if (lane == 0) {
#pragma unroll
            for (int q = 0; q < 8; ++q) h[nl][q] = acc[q] * dn;
        } else {
            h[nl][8] = acc[0] * dn;
            h[nl][9] = acc[1] * dn;
        }
    }
    __syncthreads();

    const int half = threadIdx.x & 1;
    const int nodeB = node0 + (threadIdx.x >> 1);
    if (nodeB < n) {
        float dnB = dis[nodeB];
        float hv[10];
#pragma unroll
        for (int k = 0; k < 10; ++k) hv[k] = h[threadIdx.x >> 1][k];
#pragma unroll
        for (int step = 0; step < 8; ++step) {
            int c0 = half * 64 + step * 8;
            unsigned rr[4];
#pragma unroll
            for (int cc = 0; cc < 8; cc += 2) {
                float a0 = bias[c0 + cc], a1 = bias[c0 + cc + 1];
#pragma unroll
                for (int k = 0; k < 10; ++k) {
                    a0 = fmaf(hv[k], w[k][c0 + cc], a0);
                    a1 = fmaf(hv[k], w[k][c0 + cc + 1], a1);
                }
                rr[cc >> 1] = pack2(fmaxf(a0, 0.f) * dnB, fmaxf(a1, 0.f) * dnB);
            }
            reinterpret_cast<uint4*>(out)[((size_t)nodeB * 128 + c0) >> 3] =
                make_uint4(rr[0], rr[1], rr[2], rr[3]);
        }
    }
}

// ---------------- fused agg + MFMA transform (layers 2 and 3) ----------------
// Phase A: gather 16 nodes' K-col bf16 rows (identical loop to round-14 agg;
// values bit-identical since the old SB round-trip was bf16). Packed 16B
// chunks stored to LDS with chunk-XOR swizzle (chunk ^ (row&7)).
// Phase B: MFMA 16x256 tile from LDS A-frags + register-preloaded B-frags;
// LDS-staged epilogue (bias+relu+opt dis) + 512-uint4 coalesced store.
template <int K, bool SCALE>
__global__ __launch_bounds__(THREADS, 2) void fused_layer_kernel(
        const __hip_bfloat16* __restrict__ S, const int* __restrict__ row_ptr,
        const int* __restrict__ col, const float* __restrict__ dis,
        const __hip_bfloat16* __restrict__ WT, const float* __restrict__ b,
        __hip_bfloat16* __restrict__ out, int n, int ntiles) {
    constexpr int KS = K / 32;             // 4 or 8
    constexpr int L = K / 8;               // uint4 chunks per node row (16/32)
    constexpr int NPB = THREADS / L;       // nodes gathered per pass (16/8)
    constexpr int PASSES = 16 / NPB;       // 1 or 2
    constexpr int TSTR = 264;
    __shared__ uint4 atile[16 * L];
    __shared__ __hip_bfloat16 otile[16 * TSTR];

    const int wave = threadIdx.x >> 6;
    const int lane = threadIdx.x & 63;
    const int lrow = lane & 15;
    const int lk8  = (lane >> 4) * 8;

    // ---- preload B fragments + bias (held for whole kernel) ----
    const uint4* WT4 = reinterpret_cast<const uint4*>(WT);
    bf16x8 bfr[4][KS];
    float bias[4];
#pragma unroll
    for (int ct = 0; ct < 4; ++ct) {
        int colc = wave * 64 + ct * 16 + lrow;
        bias[ct] = b[colc];
#pragma unroll
        for (int kk = 0; kk < KS; ++kk)
            bfr[ct][kk] = __builtin_bit_cast(
                bf16x8, WT4[((size_t)colc * K + kk * 32 + lk8) >> 3]);
    }

    const uint4* S4 = reinterpret_cast<const uint4*>(S);
    const int gn = threadIdx.x / L;        // node-slot within pass
    const int gl = threadIdx.x % L;        // chunk index within row

    for (int t = blockIdx.x; t < ntiles; t += gridDim.x) {
        // ---- phase A: gather 16 nodes into atile ----
#pragma unroll
        for (int ps = 0; ps < PASSES; ++ps) {
            int nl = ps * NPB + gn;        // 0..15
            int node = t * 16 + nl;
            uint4 o = make_uint4(0, 0, 0, 0);
            if (node < n) {
                float acc[8];
#pragma unroll
                for (int q = 0; q < 8; ++q) acc[q] = 0.f;
                acc8(acc, S4[(size_t)node * L + gl]);   // self-loop term

                int s = row_ptr[node], e = row_ptr[node + 1];
                int p = s;
                for (; p + 8 <= e; p += 8) {
                    int j[8];
#pragma unroll
                    for (int q = 0; q < 8; ++q) j[q] = col[p + q];
                    uint4 v[8];
#pragma unroll
                    for (int q = 0; q < 8; ++q) v[q] = S4[(size_t)j[q] * L + gl];
#pragma unroll
                    for (int q = 0; q < 8; ++q) acc8(acc, v[q]);
                }
                for (; p + 2 <= e; p += 2) {
                    int j0 = col[p], j1 = col[p + 1];
                    uint4 v0 = S4[(size_t)j0 * L + gl];
                    uint4 v1 = S4[(size_t)j1 * L + gl];
                    acc8(acc, v0); acc8(acc, v1);
                }
                for (; p < e; ++p) acc8(acc, S4[(size_t)col[p] * L + gl]);

                float d = dis[node];
                o.x = pack2(acc[0] * d, acc[1] * d);
                o.y = pack2(acc[2] * d, acc[3] * d);
                o.z = pack2(acc[4] * d, acc[5] * d);
                o.w = pack2(acc[6] * d, acc[7] * d);
            }
            atile[nl * L + (gl ^ (nl & 7))] = o;
        }
        __syncthreads();

        // ---- phase B: MFMA from atile ----
        f32x4 acc[4];
#pragma unroll
        for (int ct = 0; ct < 4; ++ct) acc[ct] = (f32x4){0.f, 0.f, 0.f, 0.f};
#pragma unroll
        for (int kk = 0; kk < KS; ++kk) {
            int chunk = kk * 4 + (lk8 >> 3);
            uint4 av = atile[lrow * L + (chunk ^ (lrow & 7))];
            bf16x8 af = __builtin_bit_cast(bf16x8, av);
#pragma unroll
            for (int ct = 0; ct < 4; ++ct)
                acc[ct] = __builtin_amdgcn_mfma_f32_16x16x32_bf16(af, bfr[ct][kk], acc[ct], 0, 0, 0);
        }

        // epilogue -> otile (bias + relu + optional dis)
        const int lrow0 = (lane >> 4) * 4;
        float dv[4];
#pragma unroll
        for (int r = 0; r < 4; ++r) {
            int rr = t * 16 + lrow0 + r;
            dv[r] = SCALE ? ((rr < n) ? dis[rr] : 0.f) : 1.f;
        }
#pragma unroll
        for (int ct = 0; ct < 4; ++ct) {
            int colc = wave * 64 + ct * 16 + lrow;
#pragma unroll
            for (int r = 0; r < 4; ++r) {
                float v = fmaxf(acc[ct][r] + bias[ct], 0.f);
                if (SCALE) v *= dv[r];
                otile[(lrow0 + r) * TSTR + colc] = __float2bfloat16(v);
            }
        }
        __syncthreads();

        // vectorized tile store: 512 uint4, coalesced
        const int base = t * 16;
        if (base + 16 <= n) {
            uint4* g = reinterpret_cast<uint4*>(out + (size_t)base * 256);
            const uint4* tl = reinterpret_cast<const uint4*>(otile);
#pragma unroll
            for (int hh = 0; hh < 2; ++hh) {
                int idx = threadIdx.x + hh * 256;      // 0..511
                int row = idx >> 5, c16 = idx & 31;
                g[idx] = tl[row * (TSTR / 8) + c16];
            }
        } else {
            for (int idx = threadIdx.x; idx < 16 * 256; idx += THREADS) {
                int rr = base + (idx >> 8);
                if (rr < n)
                    out[(size_t)rr * 256 + (idx & 255)] =
                        otile[(idx >> 8) * TSTR + (idx & 255)];
            }
        }
        __syncthreads();
    }
}

// ---------------- fused mean-pool + heads, uint4 H reads ----------------
__global__ __launch_bounds__(THREADS) void pool_heads_kernel(
        const __hip_bfloat16* __restrict__ H, const int* __restrict__ goff,
        const float* __restrict__ Wmu, const float* __restrict__ bmu,
        const float* __restrict__ Wlv, const float* __restrict__ blv,
        float* __restrict__ out, int g_total) {
    __shared__ float part[8][256];
    __shared__ float p[256];
    int g = blockIdx.x;
    int s = goff[g], e = goff[g + 1];
    int rgrp = threadIdx.x >> 5;
    int lane = threadIdx.x & 31;
    const uint4* H4 = reinterpret_cast<const uint4*>(H);

    float acc[8];
#pragma unroll
    for (int q = 0; q < 8; ++q) acc[q] = 0.f;
    for (int r = s + rgrp; r < e; r += 8)
        acc8(acc, H4[(size_t)r * 32 + lane]);
#pragma unroll
    for (int q = 0; q < 8; ++q) part[rgrp][lane * 8 + q] = acc[q];
    __syncthreads();

    int c = threadIdx.x;
    float t = 0.f;
#pragma unroll
    for (int gq = 0; gq < 8; ++gq) t += part[gq][c];
    p[c] = t / fmaxf((float)(e - s), 1.0f);
    __syncthreads();

    if (threadIdx.x < 128) {
        int cc = threadIdx.x & 63;
        bool is_mu = threadIdx.x < 64;
        const float* W = is_mu ? Wmu : Wlv;
        const float* bb = is_mu ? bmu : blv;
        float a = 0.f;
        for (int k = 0; k < 256; ++k) a = fmaf(p[k], W[k * 64 + cc], a);
        float* o = is_mu ? (out + (size_t)g * 64)
                         : (out + (size_t)g_total * 64 + (size_t)g * 64);
        o[cc] = a + bb[cc];
    }
}

extern "C" void kernel_launch(void* const* d_in, const int* in_sizes, int n_in,
                              void* d_out, int out_size, void* d_ws, size_t ws_size,
                              hipStream_t stream) {
    const float* x      = (const float*)d_in[0];
    const int*   eidx   = (const int*)d_in[1];
    const int*   batch  = (const int*)d_in[2];
    const float* W1  = (const float*)d_in[3];
    const float* b1  = (const float*)d_in[4];
    const float* W2  = (const float*)d_in[5];
    const float* b2  = (const float*)d_in[6];
    const float* W3  = (const float*)d_in[7];
    const float* b3  = (const float*)d_in[8];
    const float* Wmu = (const float*)d_in[9];
    const float* bmu = (const float*)d_in[10];
    const float* Wlv = (const float*)d_in[11];
    const float* blv = (const float*)d_in[12];
    float* out = (float*)d_out;

    const int N = in_sizes[0] / 10;
    const int E = in_sizes[1] / 2;
    const int G = out_size / 128;

    const int* src = eidx;       // edge_index[0]
    const int* dst = eidx + E;   // edge_index[1]

    // workspace carve-up (~114 MB)
    __hip_bfloat16* SA = (__hip_bfloat16*)d_ws;          // [N,256] bf16 ping
    __hip_bfloat16* SB = SA + (size_t)N * 256;           // [N,256] bf16 pong
    float* dis  = (float*)(SB + (size_t)N * 256);        // [N]
    __hip_bfloat16* W2T = (__hip_bfloat16*)(dis + N);    // [256][128]
    __hip_bfloat16* W3T = W2T + 256 * 128;               // [256][256]
    __hip_bfloat16* xd  = W3T + 256 * 256;               // [N][16] x*dis (16B-aligned)
    int* deg     = (int*)(xd + (size_t)N * 16);          // [N]
    int* row_ptr = deg + N;                              // [N+1]
    int* cursor  = row_ptr + N + 1;                      // [N]
    int* col     = cursor + N;                           // [E]
    int* goff    = col + E;                              // [G+1]
    int* bsum    = goff + G + 1;                         // [nb]

    const int ntiles = (N + 15) / 16;
    const int nb = (N + SCAN_CHUNK - 1) / SCAN_CHUNK;

    // setup: deg=1, W transposes, goff boundaries
    {
        int total = 2 * N + 128 * 256 + 256 * 256;
        setup_kernel<<<(total + THREADS - 1) / THREADS, THREADS, 0, stream>>>(
            deg, W2, W2T, W3, W3T, batch, goff, N, G);
    }
    // XCD-pinned indegree histogram (uint4 edge reads)
    hist_deg_kernel<<<2048, THREADS, 0, stream>>>(dst, deg, E, N);
    // parallel scan: partials then final (row_ptr + cursor + dis + xd pack)
    scan_part_kernel<<<nb, 1024, 0, stream>>>(deg, bsum, N);
    scan_final_kernel<<<nb, 1024, 0, stream>>>(deg, bsum, nb, row_ptr, cursor, dis, x, xd, N);
    // XCD-pinned CSR fill (uint4 edge reads)
    fill_csr_kernel<<<2048, THREADS, 0, stream>>>(src, dst, cursor, col, E, N);

    // layer 1: fused xd gather + 10->128 transform -> row-major SA [N,128]
    layer1_kernel<<<(N + 127) / 128, THREADS, 0, stream>>>(
        xd, row_ptr, col, dis, W1, b1, SA, N);

    // layer 2: fused aggregate(128) + MFMA 128->256 (*dis) -> SB [N,256]
    fused_layer_kernel<128, true><<<1024, THREADS, 0, stream>>>(
        SA, row_ptr, col, dis, W2T, b2, SB, N, ntiles);

    // layer 3: fused aggregate(256) + MFMA 256->256 -> SA [N,256]
    fused_layer_kernel<256, false><<<1024, THREADS, 0, stream>>>(
        SB, row_ptr, col, dis, W3T, b3, SA, N, ntiles);

    // fused mean pool + heads (vectorized reads)
    pool_heads_kernel<<<G, THREADS, 0, stream>>>(SA, goff, Wmu, bmu, Wlv, blv, out, G);
}

// Round 18
// 454.874 us; speedup vs baseline: 1.0346x; 1.0346x over previous
//
#include <hip/hip_runtime.h>
#include <hip/hip_bf16.h>
#include <math.h>

// GraphEncoder: 3x GCNConv (relu) -> global_mean_pool -> two linear heads.
// N=100000, E=1600000, G=2048, feats 10->128->256->256->64(x2)
//
// Round-18: layer-3 fusion REVERTED (round-17: occupancy 20.8% at lb(256,2)
// starved the request-issue-bound gather; fused256 161us > 144us separate).
// Layer-2 fusion retained with the occupancy fix: K=128 B-frags are only
// 64 VGPR -> lb(256,3) (3 blocks/CU, 12 waves, no spill) ~= separate path's
// concurrency while deleting the 26MB SB write + 26MB re-read + 1 dispatch.
// Layer 3 = round-14 agg256 + round-16 transform (proven 119 + ~25).
// All round-15/16 infrastructure frozen.

#define THREADS 256
#define SCAN_CHUNK 4096

typedef __attribute__((ext_vector_type(8))) short bf16x8;
typedef __attribute__((ext_vector_type(4))) float f32x4;

// ---------------- fused setup: deg=1, W2T, W3T, goff boundaries ----------------
__global__ void setup_kernel(int* deg,
                             const float* __restrict__ W2, __hip_bfloat16* __restrict__ W2T,
                             const float* __restrict__ W3, __hip_bfloat16* __restrict__ W3T,
                             const int* __restrict__ batch, int* goff,
                             int n, int g) {
    int i = blockIdx.x * blockDim.x + threadIdx.x;
    if (i < n) deg[i] = 1;                       // self-loop
    int r2 = i - n;
    if (r2 >= 0 && r2 < 128 * 256) {
        int k = r2 >> 8, c = r2 & 255;
        W2T[c * 128 + k] = __float2bfloat16(W2[r2]);
    }
    int r3 = i - n - 128 * 256;
    if (r3 >= 0 && r3 < 256 * 256) {
        int k = r3 >> 8, c = r3 & 255;
        W3T[c * 256 + k] = __float2bfloat16(W3[r3]);
    }
    int r4 = i - n - 128 * 256 - 256 * 256;
    if (r4 >= 0 && r4 < n) {
        int j = r4;
        int b = batch[j];
        if (j == 0) {
            for (int q = 0; q <= b; ++q) goff[q] = 0;
        } else {
            int bp = batch[j - 1];
            for (int q = bp + 1; q <= b; ++q) goff[q] = j;
        }
        if (j == n - 1) {
            for (int q = b + 1; q <= g; ++q) goff[q] = n;
        }
    }
}

// ---------------- XCD-pinned indegree histogram, uint4 edge reads -------------
__global__ __launch_bounds__(THREADS) void hist_deg_kernel(
        const int* __restrict__ dst, int* deg, int e, int n) {
    const int slice = blockIdx.x & 7;
    const int sliceSize = (n + 7) / 8;
    const int lo = slice * sliceSize;
    const int hi = lo + sliceSize;
    const int tid = (blockIdx.x >> 3) * blockDim.x + threadIdx.x;
    const int nthr = (gridDim.x >> 3) * blockDim.x;
    const int e4 = e >> 2;
    const uint4* dst4 = reinterpret_cast<const uint4*>(dst);
    for (int i = tid; i < e4; i += nthr) {
        uint4 dv = dst4[i];
        int dd[4] = {(int)dv.x, (int)dv.y, (int)dv.z, (int)dv.w};
#pragma unroll
        for (int q = 0; q < 4; ++q)
            if (dd[q] >= lo && dd[q] < hi) atomicAdd(&deg[dd[q]], 1);
    }
    for (int i = (e & ~3) + tid; i < e; i += nthr) {
        int d = dst[i];
        if (d >= lo && d < hi) atomicAdd(&deg[d], 1);
    }
}

// ---------------- parallel scan, phase 1: per-chunk indegree sums ----------------
__global__ __launch_bounds__(1024) void scan_part_kernel(
        const int* __restrict__ deg, int* __restrict__ bsum, int n) {
    __shared__ int ws[16];
    const int lane = threadIdx.x & 63;
    const int wid = threadIdx.x >> 6;
    int i0 = blockIdx.x * SCAN_CHUNK + threadIdx.x * 4;
    int s = 0;
#pragma unroll
    for (int q = 0; q < 4; ++q) {
        int i = i0 + q;
        if (i < n) s += deg[i] - 1;
    }
#pragma unroll
    for (int off = 32; off > 0; off >>= 1) s += __shfl_down(s, off, 64);
    if (lane == 0) ws[wid] = s;
    __syncthreads();
    if (threadIdx.x == 0) {
        int t = 0;
        for (int w = 0; w < 16; ++w) t += ws[w];
        bsum[blockIdx.x] = t;
    }
}

__device__ __forceinline__ unsigned pack2(float a, float b) {
    unsigned short ua = __builtin_bit_cast(unsigned short, __float2bfloat16(a));
    unsigned short ub = __builtin_bit_cast(unsigned short, __float2bfloat16(b));
    return (unsigned)ua | ((unsigned)ub << 16);
}

// ---------------- parallel scan, phase 2: scan + row_ptr/cursor/dis + xd pack ----
__global__ __launch_bounds__(1024) void scan_final_kernel(
        const int* __restrict__ deg, const int* __restrict__ bsum, int nb,
        int* __restrict__ row_ptr, int* __restrict__ cursor,
        float* __restrict__ dis, const float* __restrict__ x,
        __hip_bfloat16* __restrict__ xd, int n) {
    __shared__ int wsum[16];
    __shared__ int sbase;
    const int lane = threadIdx.x & 63;
    const int wid = threadIdx.x >> 6;
    if (threadIdx.x == 0) {
        int t = 0;
        for (int b = 0; b < blockIdx.x; ++b) t += bsum[b];
        sbase = t;
        if (blockIdx.x == 0) {
            int tot = 0;
            for (int b = 0; b < nb; ++b) tot += bsum[b];
            row_ptr[n] = tot;
        }
    }
    int i0 = blockIdx.x * SCAN_CHUNK + threadIdx.x * 4;
    int v[4];
#pragma unroll
    for (int q = 0; q < 4; ++q) {
        int i = i0 + q;
        v[q] = (i < n) ? (deg[i] - 1) : 0;
    }
    int tsum = v[0] + v[1] + v[2] + v[3];
    int incl = tsum;
#pragma unroll
    for (int off = 1; off < 64; off <<= 1) {
        int t = __shfl_up(incl, off, 64);
        if (lane >= off) incl += t;
    }
    if (lane == 63) wsum[wid] = incl;
    __syncthreads();
    int wbase = 0;
    for (int w = 0; w < wid; ++w) wbase += wsum[w];
    int pos = incl - tsum + wbase + sbase;
    uint4* xd4 = reinterpret_cast<uint4*>(xd);
#pragma unroll
    for (int q = 0; q < 4; ++q) {
        int i = i0 + q;
        if (i < n) {
            row_ptr[i] = pos;
            cursor[i] = pos;
            float dv = rsqrtf((float)(v[q] + 1));
            dis[i] = dv;
            unsigned ow[8];
#pragma unroll
            for (int k = 0; k < 5; ++k)
                ow[k] = pack2(x[(size_t)i * 10 + 2 * k] * dv,
                              x[(size_t)i * 10 + 2 * k + 1] * dv);
            ow[5] = 0; ow[6] = 0; ow[7] = 0;
            xd4[(size_t)i * 2]     = make_uint4(ow[0], ow[1], ow[2], ow[3]);
            xd4[(size_t)i * 2 + 1] = make_uint4(ow[4], ow[5], ow[6], ow[7]);
        }
        pos += v[q];
    }
}

// ---------------- XCD-pinned CSR fill, uint4 edge reads ----------------
__global__ __launch_bounds__(THREADS) void fill_csr_kernel(
        const int* __restrict__ src, const int* __restrict__ dst,
        int* cursor, int* __restrict__ col, int e, int n) {
    const int slice = blockIdx.x & 7;
    const int sliceSize = (n + 7) / 8;
    const int lo = slice * sliceSize;
    const int hi = lo + sliceSize;
    const int tid = (blockIdx.x >> 3) * blockDim.x + threadIdx.x;
    const int nthr = (gridDim.x >> 3) * blockDim.x;
    const int e4 = e >> 2;
    const uint4* dst4 = reinterpret_cast<const uint4*>(dst);
    const uint4* src4 = reinterpret_cast<const uint4*>(src);
    for (int i = tid; i < e4; i += nthr) {
        uint4 dv = dst4[i];
        int dd[4] = {(int)dv.x, (int)dv.y, (int)dv.z, (int)dv.w};
        bool any = false;
#pragma unroll
        for (int q = 0; q < 4; ++q) any |= (dd[q] >= lo && dd[q] < hi);
        if (!any) continue;
        uint4 sv = src4[i];
        int ss[4] = {(int)sv.x, (int)sv.y, (int)sv.z, (int)sv.w};
#pragma unroll
        for (int q = 0; q < 4; ++q) {
            if (dd[q] >= lo && dd[q] < hi) {
                int pos = atomicAdd(&cursor[dd[q]], 1);
                col[pos] = ss[q];
            }
        }
    }
    for (int i = (e & ~3) + tid; i < e; i += nthr) {
        int d = dst[i];
        if (d >= lo && d < hi) {
            int pos = atomicAdd(&cursor[d], 1);
            col[pos] = src[i];
        }
    }
}

// ---------------- bf16 helpers ----------------
__device__ __forceinline__ void acc8(float* acc, uint4 v) {
    acc[0] += __uint_as_float(v.x << 16);
    acc[1] += __uint_as_float(v.x & 0xffff0000u);
    acc[2] += __uint_as_float(v.y << 16);
    acc[3] += __uint_as_float(v.y & 0xffff0000u);
    acc[4] += __uint_as_float(v.z << 16);
    acc[5] += __uint_as_float(v.z & 0xffff0000u);
    acc[6] += __uint_as_float(v.w << 16);
    acc[7] += __uint_as_float(v.w & 0xffff0000u);
}

// ---------------- fused layer 1: 2-lane uint4 xd gather + 10->128 transform ----
__global__ __launch_bounds__(THREADS) void layer1_kernel(
        const __hip_bfloat16* __restrict__ xd, const int* __restrict__ row_ptr,
        const int* __restrict__ col, const float* __restrict__ dis,
        const float* __restrict__ W1, const float* __restrict__ b1,
        __hip_bfloat16* __restrict__ out, int n) {
    __shared__ float h[128][12];
    __shared__ float w[10][128];
    __shared__ float bias[128];

    for (int idx = threadIdx.x; idx < 1280; idx += THREADS)
        w[idx >> 7][idx & 127] = W1[idx];
    if (threadIdx.x < 128) bias[threadIdx.x] = b1[threadIdx.x];

    const int node0 = blockIdx.x * 128;
    const int nl = threadIdx.x >> 1;
    const int lane = threadIdx.x & 1;
    const int node = node0 + nl;
    const uint4* S4 = reinterpret_cast<const uint4*>(xd);

    if (node < n) {
        float acc[8];
#pragma unroll
        for (int q = 0; q < 8; ++q) acc[q] = 0.f;
        acc8(acc, S4[(size_t)node * 2 + lane]);   // self (xd = x*dis)

        int s = row_ptr[node], e = row_ptr[node + 1];
        int p = s;
        for (; p + 8 <= e; p += 8) {
            int j[8];
#pragma unroll
            for (int q = 0; q < 8; ++q) j[q] = col[p + q];
            uint4 v[8];
#pragma unroll
            for (int q = 0; q < 8; ++q) v[q] = S4[(size_t)j[q] * 2 + lane];
#pragma unroll
            for (int q = 0; q < 8; ++q) acc8(acc, v[q]);
        }
        for (; p < e; ++p) acc8(acc, S4[(size_t)col[p] * 2 + lane]);

        float dn = dis[node];
        if (lane == 0) {
#pragma unroll
            for (int q = 0; q < 8; ++q) h[nl][q] = acc[q] * dn;
        } else {
            h[nl][8] = acc[0] * dn;
            h[nl][9] = acc[1] * dn;
        }
    }
    __syncthreads();

    const int half = threadIdx.x & 1;
    const int nodeB = node0 + (threadIdx.x >> 1);
    if (nodeB < n) {
        float dnB = dis[nodeB];
        float hv[10];
#pragma unroll
        for (int k = 0; k < 10; ++k) hv[k] = h[threadIdx.x >> 1][k];
#pragma unroll
        for (int step = 0; step < 8; ++step) {
            int c0 = half * 64 + step * 8;
            unsigned rr[4];
#pragma unroll
            for (int cc = 0; cc < 8; cc += 2) {
                float a0 = bias[c0 + cc], a1 = bias[c0 + cc + 1];
#pragma unroll
                for (int k = 0; k < 10; ++k) {
                    a0 = fmaf(hv[k], w[k][c0 + cc], a0);
                    a1 = fmaf(hv[k], w[k][c0 + cc + 1], a1);
                }
                rr[cc >> 1] = pack2(fmaxf(a0, 0.f) * dnB, fmaxf(a1, 0.f) * dnB);
            }
            reinterpret_cast<uint4*>(out)[((size_t)nodeB * 128 + c0) >> 3] =
                make_uint4(rr[0], rr[1], rr[2], rr[3]);
        }
    }
}

// ---------------- agg over COLS-col bf16 rows; L = COLS/8 lanes/node (row-major) ----
template <int COLS, int L>
__global__ __launch_bounds__(THREADS) void agg_bf16_kernel(
        const __hip_bfloat16* __restrict__ S, const int* __restrict__ row_ptr,
        const int* __restrict__ col, const float* __restrict__ dis,
        __hip_bfloat16* __restrict__ out, int n) {
    static_assert(L * 8 == COLS, "");
    constexpr int stride = COLS / 8;       // uint4 per row
    int node = blockIdx.x * (THREADS / L) + threadIdx.x / L;
    if (node >= n) return;
    int lane = threadIdx.x % L;
    const uint4* S4 = reinterpret_cast<const uint4*>(S);

    float acc[8];
#pragma unroll
    for (int q = 0; q < 8; ++q) acc[q] = 0.f;
    acc8(acc, S4[(size_t)node * stride + lane]);   // self-loop term

    int s = row_ptr[node], e = row_ptr[node + 1];
    int p = s;
    for (; p + 8 <= e; p += 8) {
        int j[8];
#pragma unroll
        for (int q = 0; q < 8; ++q) j[q] = col[p + q];
        uint4 v[8];
#pragma unroll
        for (int q = 0; q < 8; ++q) v[q] = S4[(size_t)j[q] * stride + lane];
#pragma unroll
        for (int q = 0; q < 8; ++q) acc8(acc, v[q]);
    }
    for (; p + 2 <= e; p += 2) {
        int j0 = col[p], j1 = col[p + 1];
        uint4 v0 = S4[(size_t)j0 * stride + lane];
        uint4 v1 = S4[(size_t)j1 * stride + lane];
        acc8(acc, v0); acc8(acc, v1);
    }
    for (; p < e; ++p) acc8(acc, S4[(size_t)col[p] * stride + lane]);

    float d = dis[node];
    uint4 o;
    o.x = pack2(acc[0] * d, acc[1] * d);
    o.y = pack2(acc[2] * d, acc[3] * d);
    o.z = pack2(acc[4] * d, acc[5] * d);
    o.w = pack2(acc[6] * d, acc[7] * d);
    reinterpret_cast<uint4*>(out)[(size_t)node * stride + lane] = o;
}

// ---------------- fused agg(128) + MFMA 128->256 transform (layer 2) ----------
// K=128 only: B-frags = 64 VGPR -> lb(256,3) keeps 12 waves/CU (round-17's
// K=256 version at lb(256,2) had 8 waves -> gather starved).
__global__ __launch_bounds__(THREADS, 3) void fused128_kernel(
        const __hip_bfloat16* __restrict__ S, const int* __restrict__ row_ptr,
        const int* __restrict__ col, const float* __restrict__ dis,
        const __hip_bfloat16* __restrict__ WT, const float* __restrict__ b,
        __hip_bfloat16* __restrict__ out, int n, int ntiles) {
    constexpr int K = 128, KS = 4, L = 16, TSTR = 264;
    __shared__ uint4 atile[16 * L];
    __shared__ __hip_bfloat16 otile[16 * TSTR];

    const int wave = threadIdx.x >> 6;
    const int lane = threadIdx.x & 63;
    const int lrow = lane & 15;
    const int lk8  = (lane >> 4) * 8;

    const uint4* WT4 = reinterpret_cast<const uint4*>(WT);
    bf16x8 bfr[4][KS];
    float bias[4];
#pragma unroll
    for (int ct = 0; ct < 4; ++ct) {
        int colc = wave * 64 + ct * 16 + lrow;
        bias[ct] = b[colc];
#pragma unroll
        for (int kk = 0; kk < KS; ++kk)
            bfr[ct][kk] = __builtin_bit_cast(
                bf16x8, WT4[((size_t)colc * K + kk * 32 + lk8) >> 3]);
    }

    const uint4* S4 = reinterpret_cast<const uint4*>(S);
    const int gn = threadIdx.x / L;        // node-slot 0..15
    const int gl = threadIdx.x % L;        // chunk 0..15

    for (int t = blockIdx.x; t < ntiles; t += gridDim.x) {
        // ---- phase A: gather 16 nodes into atile (bit-identical agg loop) ----
        {
            int node = t * 16 + gn;
            uint4 o = make_uint4(0, 0, 0, 0);
            if (node < n) {
                float acc[8];
#pragma unroll
                for (int q = 0; q < 8; ++q) acc[q] = 0.f;
                acc8(acc, S4[(size_t)node * L + gl]);

                int s = row_ptr[node], e = row_ptr[node + 1];
                int p = s;
                for (; p + 8 <= e; p += 8) {
                    int j[8];
#pragma unroll
                    for (int q = 0; q < 8; ++q) j[q] = col[p + q];
                    uint4 v[8];
#pragma unroll
                    for (int q = 0; q < 8; ++q) v[q] = S4[(size_t)j[q] * L + gl];
#pragma unroll
                    for (int q = 0; q < 8; ++q) acc8(acc, v[q]);
                }
                for (; p + 2 <= e; p += 2) {
                    int j0 = col[p], j1 = col[p + 1];
                    uint4 v0 = S4[(size_t)j0 * L + gl];
                    uint4 v1 = S4[(size_t)j1 * L + gl];
                    acc8(acc, v0); acc8(acc, v1);
                }
                for (; p < e; ++p) acc8(acc, S4[(size_t)col[p] * L + gl]);

                float d = dis[node];
                o.x = pack2(acc[0] * d, acc[1] * d);
                o.y = pack2(acc[2] * d, acc[3] * d);
                o.z = pack2(acc[4] * d, acc[5] * d);
                o.w = pack2(acc[6] * d, acc[7] * d);
            }
            atile[gn * L + (gl ^ (gn & 7))] = o;
        }
        __syncthreads();

        // ---- phase B: MFMA from atile ----
        f32x4 acc[4];
#pragma unroll
        for (int ct = 0; ct < 4; ++ct) acc[ct] = (f32x4){0.f, 0.f, 0.f, 0.f};
#pragma unroll
        for (int kk = 0; kk < KS; ++kk) {
            int chunk = kk * 4 + (lk8 >> 3);
            uint4 av = atile[lrow * L + (chunk ^ (lrow & 7))];
            bf16x8 af = __builtin_bit_cast(bf16x8, av);
#pragma unroll
            for (int ct = 0; ct < 4; ++ct)
                acc[ct] = __builtin_amdgcn_mfma_f32_16x16x32_bf16(af, bfr[ct][kk], acc[ct], 0, 0, 0);
        }

        // epilogue -> otile (bias + relu + dis)
        const int lrow0 = (lane >> 4) * 4;
        float dv[4];
#pragma unroll
        for (int r = 0; r < 4; ++r) {
            int rr = t * 16 + lrow0 + r;
            dv[r] = (rr < n) ? dis[rr] : 0.f;
        }
#pragma unroll
        for (int ct = 0; ct < 4; ++ct) {
            int colc = wave * 64 + ct * 16 + lrow;
#pragma unroll
            for (int r = 0; r < 4; ++r) {
                float v = fmaxf(acc[ct][r] + bias[ct], 0.f) * dv[r];
                otile[(lrow0 + r) * TSTR + colc] = __float2bfloat16(v);
            }
        }
        __syncthreads();

        // vectorized tile store
        const int base = t * 16;
        if (base + 16 <= n) {
            uint4* g = reinterpret_cast<uint4*>(out + (size_t)base * 256);
            const uint4* tl = reinterpret_cast<const uint4*>(otile);
#pragma unroll
            for (int hh = 0; hh < 2; ++hh) {
                int idx = threadIdx.x + hh * 256;
                int row = idx >> 5, c16 = idx & 31;
                g[idx] = tl[row * (TSTR / 8) + c16];
            }
        } else {
            for (int idx = threadIdx.x; idx < 16 * 256; idx += THREADS) {
                int rr = base + (idx >> 8);
                if (rr < n)
                    out[(size_t)rr * 256 + (idx & 255)] =
                        otile[(idx >> 8) * TSTR + (idx & 255)];
            }
        }
        __syncthreads();
    }
}

// ---------------- MFMA transform v3 (layer 3): LDS-staged vectorized epilogue ----
template <int K, bool SCALE>
__global__ __launch_bounds__(THREADS) void transform_mfma2_kernel(
        const __hip_bfloat16* __restrict__ A, const __hip_bfloat16* __restrict__ WT,
        const float* __restrict__ b, const float* __restrict__ dis,
        __hip_bfloat16* __restrict__ out, int n, int ntiles) {
    constexpr int KS = K / 32;
    constexpr int TSTR = 264;
    __shared__ __hip_bfloat16 tile[16 * TSTR];
    const int wave = threadIdx.x >> 6;
    const int lane = threadIdx.x & 63;
    const int lrow = lane & 15;
    const int lk8  = (lane >> 4) * 8;

    const uint4* WT4 = reinterpret_cast<const uint4*>(WT);
    bf16x8 bfr[4][KS];
    float bias[4];
#pragma unroll
    for (int ct = 0; ct < 4; ++ct) {
        int colc = wave * 64 + ct * 16 + lrow;
        bias[ct] = b[colc];
#pragma unroll
        for (int kk = 0; kk < KS; ++kk)
            bfr[ct][kk] = __builtin_bit_cast(
                bf16x8, WT4[((size_t)colc * K + kk * 32 + lk8) >> 3]);
    }

    const uint4* A4 = reinterpret_cast<const uint4*>(A);
    auto loadA = [&](int t, uint4* av) {
        int row = t * 16 + lrow;
        if (row >= n) row = n - 1;
#pragma unroll
        for (int kk = 0; kk < KS; ++kk)
            av[kk] = A4[((size_t)row * K + kk * 32 + lk8) >> 3];
    };

    uint4 aC[KS], aN[KS];
    int t = blockIdx.x;
    if (t < ntiles) loadA(t, aC);

    for (; t < ntiles; t += gridDim.x) {
        int tn = t + gridDim.x;
        if (tn < ntiles) loadA(tn, aN);

        f32x4 acc[4];
#pragma unroll
        for (int ct = 0; ct < 4; ++ct) acc[ct] = (f32x4){0.f, 0.f, 0.f, 0.f};
#pragma unroll
        for (int kk = 0; kk < KS; ++kk) {
            bf16x8 af = __builtin_bit_cast(bf16x8, aC[kk]);
#pragma unroll
            for (int ct = 0; ct < 4; ++ct)
                acc[ct] = __builtin_amdgcn_mfma_f32_16x16x32_bf16(af, bfr[ct][kk], acc[ct], 0, 0, 0);
        }

        const int lrow0 = (lane >> 4) * 4;
        float dv[4];
#pragma unroll
        for (int r = 0; r < 4; ++r) {
            int rr = t * 16 + lrow0 + r;
            dv[r] = SCALE ? ((rr < n) ? dis[rr] : 0.f) : 1.f;
        }
#pragma unroll
        for (int ct = 0; ct < 4; ++ct) {
            int colc = wave * 64 + ct * 16 + lrow;
#pragma unroll
            for (int r = 0; r < 4; ++r) {
                float v = fmaxf(acc[ct][r] + bias[ct], 0.f);
                if (SCALE) v *= dv[r];
                tile[(lrow0 + r) * TSTR + colc] = __float2bfloat16(v);
            }
        }
        __syncthreads();

        const int base = t * 16;
        if (base + 16 <= n) {
            uint4* g = reinterpret_cast<uint4*>(out + (size_t)base * 256);
            const uint4* tl = reinterpret_cast<const uint4*>(tile);
#pragma unroll
            for (int h = 0; h < 2; ++h) {
                int idx = threadIdx.x + h * 256;
                int row = idx >> 5, c16 = idx & 31;
                g[idx] = tl[row * (TSTR / 8) + c16];
            }
        } else {
            for (int idx = threadIdx.x; idx < 16 * 256; idx += THREADS) {
                int rr = base + (idx >> 8);
                if (rr < n) out[(size_t)rr * 256 + (idx & 255)] = tile[(idx >> 8) * TSTR + (idx & 255)];
            }
        }
        __syncthreads();

#pragma unroll
        for (int kk = 0; kk < KS; ++kk) aC[kk] = aN[kk];
    }
}

// ---------------- fused mean-pool + heads, uint4 H reads ----------------
__global__ __launch_bounds__(THREADS) void pool_heads_kernel(
        const __hip_bfloat16* __restrict__ H, const int* __restrict__ goff,
        const float* __restrict__ Wmu, const float* __restrict__ bmu,
        const float* __restrict__ Wlv, const float* __restrict__ blv,
        float* __restrict__ out, int g_total) {
    __shared__ float part[8][256];
    __shared__ float p[256];
    int g = blockIdx.x;
    int s = goff[g], e = goff[g + 1];
    int rgrp = threadIdx.x >> 5;
    int lane = threadIdx.x & 31;
    const uint4* H4 = reinterpret_cast<const uint4*>(H);

    float acc[8];
#pragma unroll
    for (int q = 0; q < 8; ++q) acc[q] = 0.f;
    for (int r = s + rgrp; r < e; r += 8)
        acc8(acc, H4[(size_t)r * 32 + lane]);
#pragma unroll
    for (int q = 0; q < 8; ++q) part[rgrp][lane * 8 + q] = acc[q];
    __syncthreads();

    int c = threadIdx.x;
    float t = 0.f;
#pragma unroll
    for (int gq = 0; gq < 8; ++gq) t += part[gq][c];
    p[c] = t / fmaxf((float)(e - s), 1.0f);
    __syncthreads();

    if (threadIdx.x < 128) {
        int cc = threadIdx.x & 63;
        bool is_mu = threadIdx.x < 64;
        const float* W = is_mu ? Wmu : Wlv;
        const float* bb = is_mu ? bmu : blv;
        float a = 0.f;
        for (int k = 0; k < 256; ++k) a = fmaf(p[k], W[k * 64 + cc], a);
        float* o = is_mu ? (out + (size_t)g * 64)
                         : (out + (size_t)g_total * 64 + (size_t)g * 64);
        o[cc] = a + bb[cc];
    }
}

extern "C" void kernel_launch(void* const* d_in, const int* in_sizes, int n_in,
                              void* d_out, int out_size, void* d_ws, size_t ws_size,
                              hipStream_t stream) {
    const float* x      = (const float*)d_in[0];
    const int*   eidx   = (const int*)d_in[1];
    const int*   batch  = (const int*)d_in[2];
    const float* W1  = (const float*)d_in[3];
    const float* b1  = (const float*)d_in[4];
    const float* W2  = (const float*)d_in[5];
    const float* b2  = (const float*)d_in[6];
    const float* W3  = (const float*)d_in[7];
    const float* b3  = (const float*)d_in[8];
    const float* Wmu = (const float*)d_in[9];
    const float* bmu = (const float*)d_in[10];
    const float* Wlv = (const float*)d_in[11];
    const float* blv = (const float*)d_in[12];
    float* out = (float*)d_out;

    const int N = in_sizes[0] / 10;
    const int E = in_sizes[1] / 2;
    const int G = out_size / 128;

    const int* src = eidx;       // edge_index[0]
    const int* dst = eidx + E;   // edge_index[1]

    // workspace carve-up (~114 MB)
    __hip_bfloat16* SA = (__hip_bfloat16*)d_ws;          // [N,256] bf16 ping
    __hip_bfloat16* SB = SA + (size_t)N * 256;           // [N,256] bf16 pong
    float* dis  = (float*)(SB + (size_t)N * 256);        // [N]
    __hip_bfloat16* W2T = (__hip_bfloat16*)(dis + N);    // [256][128]
    __hip_bfloat16* W3T = W2T + 256 * 128;               // [256][256]
    __hip_bfloat16* xd  = W3T + 256 * 256;               // [N][16] x*dis
    int* deg     = (int*)(xd + (size_t)N * 16);          // [N]
    int* row_ptr = deg + N;                              // [N+1]
    int* cursor  = row_ptr + N + 1;                      // [N]
    int* col     = cursor + N;                           // [E]
    int* goff    = col + E;                              // [G+1]
    int* bsum    = goff + G + 1;                         // [nb]

    const int ntiles = (N + 15) / 16;
    const int nb = (N + SCAN_CHUNK - 1) / SCAN_CHUNK;

    // setup: deg=1, W transposes, goff boundaries
    {
        int total = 2 * N + 128 * 256 + 256 * 256;
        setup_kernel<<<(total + THREADS - 1) / THREADS, THREADS, 0, stream>>>(
            deg, W2, W2T, W3, W3T, batch, goff, N, G);
    }
    // XCD-pinned indegree histogram (uint4 edge reads)
    hist_deg_kernel<<<2048, THREADS, 0, stream>>>(dst, deg, E, N);
    // parallel scan: partials then final (row_ptr + cursor + dis + xd pack)
    scan_part_kernel<<<nb, 1024, 0, stream>>>(deg, bsum, N);
    scan_final_kernel<<<nb, 1024, 0, stream>>>(deg, bsum, nb, row_ptr, cursor, dis, x, xd, N);
    // XCD-pinned CSR fill (uint4 edge reads)
    fill_csr_kernel<<<2048, THREADS, 0, stream>>>(src, dst, cursor, col, E, N);

    // layer 1: fused xd gather + 10->128 transform -> row-major SA [N,128]
    layer1_kernel<<<(N + 127) / 128, THREADS, 0, stream>>>(
        xd, row_ptr, col, dis, W1, b1, SA, N);

    // layer 2: FUSED aggregate(128) + MFMA 128->256 (*dis) -> SB [N,256]
    fused128_kernel<<<2048, THREADS, 0, stream>>>(
        SA, row_ptr, col, dis, W2T, b2, SB, N, ntiles);

    // layer 3: separate aggregate(256) SB -> SA, then MFMA 256->256 SA -> SB
    agg_bf16_kernel<256, 32><<<(N + 7) / 8, THREADS, 0, stream>>>(SB, row_ptr, col, dis, SA, N);
    transform_mfma2_kernel<256, false><<<512, THREADS, 0, stream>>>(SA, W3T, b3, dis, SB, N, ntiles);

    // fused mean pool + heads (vectorized reads, layer-3 output in SB)
    pool_heads_kernel<<<G, THREADS, 0, stream>>>(SB, goff, Wmu, bmu, Wlv, blv, out, G);
}